// Round 17
// baseline (378.810 us; speedup 1.0000x reference)
//
#include <hip/hip_runtime.h>
#include <hip/hip_bf16.h>
#include <cstdint>
#include <cstddef>

typedef short s16x8 __attribute__((ext_vector_type(8)));
typedef float f32x4 __attribute__((ext_vector_type(4)));

#define DEV static __device__ __forceinline__

DEV unsigned short f2bf(float x){
  union { float f; unsigned int u; } v; v.f = x;
  unsigned int u = v.u;
  return (unsigned short)((u + 0x7FFFu + ((u >> 16) & 1u)) >> 16);
}
DEV float bf2f(unsigned short b){
  union { unsigned int u; float f; } v; v.u = ((unsigned int)b) << 16;
  return v.f;
}
DEV void ntst(float* p, float v){ __builtin_nontemporal_store(v, p); }
DEV void ntst8(void* p, unsigned long long v){
  __builtin_nontemporal_store(v, (unsigned long long*)p);
}

// raw workgroup barrier: wait LDS ops only (no vmcnt drain)
DEV void bar_lgkm(){
  asm volatile("s_waitcnt lgkmcnt(0)" ::: "memory");
  __builtin_amdgcn_s_barrier();
  __builtin_amdgcn_sched_barrier(0);
}

// async global->LDS 16B (wave-uniform LDS base + lane*16; global addr per-lane)
DEV void gld16(unsigned short* lds, const unsigned short* g){
  __builtin_amdgcn_global_load_lds(
      (const __attribute__((address_space(1))) void*)g,
      (__attribute__((address_space(3))) void*)lds, 16, 0, 0);
}

// ---------------- cast & gather (fused) ----------------
__global__ __launch_bounds__(256) void cast_x(const float* __restrict__ X,
                                              unsigned short* __restrict__ out,
                                              unsigned short* __restrict__ Xg){
  int i = (blockIdx.x*256 + threadIdx.x)*4;
  float4 v = *(const float4*)(X + i);
  ushort4 r;
  r.x = f2bf(v.x); r.y = f2bf(v.y); r.z = f2bf(v.z); r.w = f2bf(v.w);
  *(ushort4*)(out + i) = r;
  int row = i >> 10;
  int s = row & 4095, b = row >> 12;
  if (s < 64)
    *(ushort4*)(Xg + (size_t)(b*64 + s)*1024 + (i & 1023)) = r;
}

__global__ __launch_bounds__(256) void bias_cat_k(
    const float* bq, const float* bk, const float* bv,
    const float* bkg, const float* bvg, const float* bqg,
    float* __restrict__ bc, float* __restrict__ bqg_o){
  int i = blockIdx.x*256 + threadIdx.x;             // < 6144
  if (i < 5120){
    int slot = i >> 10, c = i & 1023;
    const float* s = (slot==0)?bq:(slot==1)?bk:(slot==2)?bv:(slot==3)?bkg:bvg;
    bc[i] = s[c];
  } else {
    bqg_o[i-5120] = bqg[i-5120];
  }
}

// ---------------- weight transpose: W[k][n] fp32 -> Wt[n][k] bf16 ----------------
struct WSrc { const float* p[6]; };

__global__ __launch_bounds__(256) void wt_transpose(WSrc srcs,
    unsigned short* __restrict__ Wtcat, unsigned short* __restrict__ Wtqg){
  __shared__ float t[64*66];
  int bi = blockIdx.x;
  int widx = bi >> 8;                 // 0..5 input order q,k,v,qg,kg,vg
  int tile = bi & 255;
  int tn = tile & 15, tk = tile >> 4;
  int k0 = tk*64, n0 = tn*64;
  const float* W = srcs.p[widx];
  int tid = threadIdx.x;
  for (int it=0; it<8; ++it){
    int flat = it*256 + tid;
    int r = flat >> 5, ch = flat & 31;
    *(float2*)&t[r*66 + ch*2] = *(const float2*)(W + (size_t)(k0+r)*1024 + n0 + ch*2);
  }
  __syncthreads();
  unsigned short* dst = (widx==3) ? Wtqg
                      : Wtcat + (size_t)((widx<3)?widx:widx-1)*1048576;
  for (int it=0; it<16; ++it){
    int flat = it*256 + tid;
    int i = flat >> 6, j = flat & 63;
    dst[(size_t)(n0+i)*1024 + k0 + j] = f2bf(t[j*66 + i]);
  }
}

// ---------------- 256x256 counted-vmcnt pipelined GEMM; epilogue emits v^T ----
#define G8_LDS 131072
__global__ __launch_bounds__(512) void gemm8(
    const unsigned short* __restrict__ A, const unsigned short* __restrict__ Bt,
    const float* __restrict__ bias, unsigned short* __restrict__ C,
    unsigned short* __restrict__ vtv,          // [2][16][64][4096] v^T out
    int Astr, int Bstr, int Cstr, int scale_cols)
{
  extern __shared__ unsigned short lds[];   // slot s at s*16384; B at +8192
  int tid = threadIdx.x, lane = tid & 63, wv = tid >> 6;
  int wr = wv >> 2, wc = wv & 3;
  int lane15 = lane & 15, kh = (lane >> 4) << 3;
  int m0 = blockIdx.y*256, n0 = blockIdx.x*256;

  f32x4 acc[8][4];
#pragma unroll
  for (int i=0;i<8;i++)
#pragma unroll
    for (int j=0;j<4;j++) acc[i][j] = (f32x4){0.f,0.f,0.f,0.f};

#pragma unroll
  for (int ht=0; ht<4; ++ht){
    int ktn = ht>>1, half = ht&1;
    unsigned short* sA = lds + (ht&3)*16384;
    unsigned short* sB = sA + 8192;
#pragma unroll
    for (int cc=0; cc<2; ++cc){
      int c = cc*512 + tid, r = c>>3, ch = c&7;
      int co = ktn*64 + ((ch ^ (r&7))<<3);
      gld16(sA + c*8, A  + (size_t)(m0 + half*128 + r)*Astr + co);
      gld16(sB + c*8, Bt + (size_t)(n0 + half*128 + r)*Bstr + co);
    }
  }
  asm volatile("s_waitcnt vmcnt(8)" ::: "memory");
  __builtin_amdgcn_s_barrier();
  __builtin_amdgcn_sched_barrier(0);

  for (int kt = 0; kt < 16; ++kt){
    unsigned short* aslot = lds + ((2*kt + wr)&3)*16384;
    unsigned short* bslot = lds + ((2*kt + (wc>>1))&3)*16384 + 8192;
    s16x8 bfr[4][2];
#pragma unroll
    for (int n=0;n<4;n++){
      int r = (wc&1)*64 + n*16 + lane15;
#pragma unroll
      for (int ks=0;ks<2;ks++)
        bfr[n][ks] = *(const s16x8*)&bslot[(r<<6) + ((ks*32 + kh) ^ ((r&7)<<3))];
    }
    __builtin_amdgcn_s_setprio(1);
#pragma unroll
    for (int m=0;m<8;m++){
      int r = m*16 + lane15;
      s16x8 a0 = *(const s16x8*)&aslot[(r<<6) + (kh ^ ((r&7)<<3))];
      s16x8 a1 = *(const s16x8*)&aslot[(r<<6) + ((32 + kh) ^ ((r&7)<<3))];
#pragma unroll
      for (int n=0;n<4;n++){
        acc[m][n] = __builtin_amdgcn_mfma_f32_16x16x32_bf16(a0, bfr[n][0], acc[m][n], 0,0,0);
        acc[m][n] = __builtin_amdgcn_mfma_f32_16x16x32_bf16(a1, bfr[n][1], acc[m][n], 0,0,0);
      }
    }
    __builtin_amdgcn_s_setprio(0);
    bar_lgkm();
    if (kt < 14){
#pragma unroll
      for (int hh=0; hh<2; ++hh){
        int ht = 2*kt + 4 + hh;
        int ktn = ht>>1, half = ht&1;
        unsigned short* sA = lds + (ht&3)*16384;
        unsigned short* sB = sA + 8192;
#pragma unroll
        for (int cc=0; cc<2; ++cc){
          int c = cc*512 + tid, r = c>>3, ch = c&7;
          int co = ktn*64 + ((ch ^ (r&7))<<3);
          gld16(sA + c*8, A  + (size_t)(m0 + half*128 + r)*Astr + co);
          gld16(sB + c*8, Bt + (size_t)(n0 + half*128 + r)*Bstr + co);
        }
      }
      asm volatile("s_waitcnt vmcnt(8)" ::: "memory");
    } else {
      asm volatile("s_waitcnt vmcnt(0)" ::: "memory");
    }
    __builtin_amdgcn_s_barrier();
    __builtin_amdgcn_sched_barrier(0);
  }

  // epilogue: C write + fused v^T emission (cols 2048..3071)
#pragma unroll
  for (int m=0;m<8;m++){
    int mb = m0 + wr*128 + m*16 + ((lane>>4)<<2);
#pragma unroll
    for (int n=0;n<4;n++){
      int col = n0 + wc*64 + n*16 + lane15;
      float bb = bias[col];
      float sc = (col < scale_cols) ? 0.125f : 1.0f;
      unsigned short t4[4];
#pragma unroll
      for (int r=0;r<4;r++){
        unsigned short bv = f2bf((acc[m][n][r] + bb)*sc);
        t4[r] = bv;
        C[(size_t)(mb+r)*Cstr + col] = bv;
      }
      if (col >= 2048 && col < 3072){
        int cz = col - 2048;
        int h = cz >> 6, d = cz & 63;
        int b2 = mb >> 12, ss = mb & 4095;
        unsigned long long pack;
        __builtin_memcpy(&pack, t4, 8);
        ntst8(vtv + (((size_t)(b2*16 + h)*64 + d)*4096 + ss), pack);
      }
    }
  }
}

// ---------------- proj col-slice -> t[b][h][d][s] (vg^T only now) ----------------
__global__ __launch_bounds__(256) void vt_transpose(
    const unsigned short* __restrict__ proj, unsigned short* __restrict__ dst,
    int coloff){
  __shared__ unsigned short t[64*72];
  int bi = blockIdx.x;
  int sc = bi & 63, h = (bi>>6) & 15, b = bi >> 10;
  int s0 = sc*64;
  int tid = threadIdx.x;
  for (int it=0; it<2; ++it){
    int flat = it*256 + tid;
    int r = flat >> 3, ch = flat & 7;
    *(int4*)&t[r*72 + ch*8] =
      *(const int4*)(proj + (size_t)(b*4096+s0+r)*5120 + coloff + h*64 + ch*8);
  }
  __syncthreads();
  for (int it=0; it<2; ++it){
    int flat = it*256 + tid;
    int d = flat & 63, ch = flat >> 6;
    unsigned short tmp[8];
#pragma unroll
    for (int j=0;j<8;j++) tmp[j] = t[(ch*8+j)*72 + d];
    *(int4*)(dst + ((size_t)(b*16+h)*64 + d)*4096 + s0 + ch*8) = *(int4*)tmp;
  }
}

// ---------------- small qg GEMM, K-split (4 slices x 8 n-tiles) ----------------
__global__ __launch_bounds__(256) void gemm_qg(
    const unsigned short* __restrict__ A, const unsigned short* __restrict__ Bt,
    float* __restrict__ part)
{
  __shared__ unsigned short lA[128*64];
  __shared__ unsigned short lB[128*64];
  int tid = threadIdx.x, lane = tid & 63, wv = tid >> 6;
  int wm = wv >> 1, wn = wv & 1;
  int lane15 = lane & 15, kh = (lane >> 4) << 3;
  int n0 = blockIdx.x*128, kb = blockIdx.y;
  f32x4 acc[4][4];
  for (int i=0;i<4;i++) for (int j=0;j<4;j++) acc[i][j] = (f32x4){0.f,0.f,0.f,0.f};
  for (int k0 = kb*256; k0 < kb*256 + 256; k0 += 64){
#pragma unroll
    for (int it = 0; it < 4; ++it){
      int chunk = it*256 + tid;
      int r = chunk >> 3, ch = chunk & 7;
      int co = ((ch ^ (r & 7)) << 3);
      gld16(&lA[chunk*8], A  + (size_t)r*1024 + k0 + co);
      gld16(&lB[chunk*8], Bt + (size_t)(n0+r)*1024 + k0 + co);
    }
    __syncthreads();
#pragma unroll
    for (int ks = 0; ks < 2; ++ks){
      s16x8 af[4], bfr[4];
#pragma unroll
      for (int i=0;i<4;i++){
        int row = wm*64 + i*16 + lane15;
        af[i] = *(const s16x8*)&lA[(row<<6) + ((ks*32 + kh) ^ ((row&7)<<3))];
      }
#pragma unroll
      for (int j=0;j<4;j++){
        int row = wn*64 + j*16 + lane15;
        bfr[j] = *(const s16x8*)&lB[(row<<6) + ((ks*32 + kh) ^ ((row&7)<<3))];
      }
#pragma unroll
      for (int i=0;i<4;i++)
#pragma unroll
        for (int j=0;j<4;j++)
          acc[i][j] = __builtin_amdgcn_mfma_f32_16x16x32_bf16(af[i], bfr[j], acc[i][j], 0,0,0);
    }
    __syncthreads();
  }
  float* o = part + (size_t)kb*131072;
  for (int i=0;i<4;i++){
    int mb = wm*64 + i*16 + ((lane>>4)<<2);
    for (int j=0;j<4;j++){
      int n = n0 + wn*64 + j*16 + lane15;
#pragma unroll
      for (int r=0;r<4;r++)
        ntst(o + (size_t)(mb+r)*1024 + n, acc[i][j][r]);
    }
  }
}

__global__ __launch_bounds__(256) void reduce_qg(
    const float* __restrict__ part, const float* __restrict__ bqg,
    unsigned short* __restrict__ qgo){
  int i = blockIdx.x*256 + threadIdx.x;   // < 131072
  float s = part[i] + part[131072 + i] + part[262144 + i] + part[393216 + i];
  qgo[i] = f2bf((s + bqg[i & 1023]) * 0.125f);
}

// ---------------- fused sliding-window + global-prefix attention ----------------
#define SSTR 612
__global__ __launch_bounds__(512) void sliding_attn(
    const unsigned short* __restrict__ proj,
    const unsigned short* __restrict__ vt,
    const float* __restrict__ amask,
    const unsigned char* __restrict__ maskb,
    float* __restrict__ probs,
    float* __restrict__ attn)
{
  __shared__ float sS[16*SSTR];
  __shared__ float srs[16];
  int bi = (blockIdx.x & 7)*1024 + (blockIdx.x >> 3);
  int ti = bi & 255, h = (bi>>8) & 15, b = bi >> 12;
  int t = ti*16;
  int chk = t >> 8;
  int qu = (chk < 15) ? chk*256 : 3584;
  int ql = (chk >= 1) ? chk*256 : 256;
  int tid = threadIdx.x, lane = tid & 63, wv = tid >> 6;
  int lane15 = lane & 15, kh = (lane >> 4) << 3;
  int rbase = (lane>>4)<<2;

  s16x8 aq0 = {}, aq1 = {}, ak0a = {}, ak0b = {}, ak1a = {}, ak1b = {};
  {
    int qrow = t + lane15;
    if (wv == 0){
      const unsigned short* qp = proj + (size_t)(b*4096+qrow)*5120 + h*64 + kh;
      aq0 = *(const s16x8*)qp;  aq1 = *(const s16x8*)(qp + 32);
    }
    if (wv >= 4){
      const unsigned short* kp0 = proj + (size_t)(b*4096+qrow)*5120 + 1024 + h*64 + kh;
      ak0a = *(const s16x8*)kp0; ak0b = *(const s16x8*)(kp0 + 32);
    }
    if (wv <= 3){
      int krow = t - 1 + lane15; if (krow < 0) krow = 0;
      const unsigned short* kp1 = proj + (size_t)(b*4096+krow)*5120 + 1024 + h*64 + kh;
      ak1a = *(const s16x8*)kp1; ak1b = *(const s16x8*)(kp1 + 32);
    }
  }

  {
    int ct0 = wv*5;
#pragma unroll
    for (int j5 = 0; j5 < 5; ++j5){
      int ct = ct0 + j5;
      if (ct < 37){
        int col = ct*16 + lane15;
        int brow, roff;
        if (ct < 4){        brow = col;               roff = 1024; }
        else if (ct < 20){  brow = ql + 1 + col - 64; roff = 0;
                            if (brow > 4095) brow = 4095; }
        else {              brow = qu + col - 320;    roff = 0; }
        const unsigned short* bp = proj + (size_t)(b*4096+brow)*5120 + roff + h*64 + kh;
        s16x8 b0 = *(const s16x8*)bp;
        s16x8 b1 = *(const s16x8*)(bp + 32);
        s16x8 A0 = (ct<4) ? aq0 : (ct<20) ? ak1a : ak0a;
        s16x8 A1 = (ct<4) ? aq1 : (ct<20) ? ak1b : ak0b;
        f32x4 acc = (f32x4){0.f,0.f,0.f,0.f};
        __builtin_amdgcn_s_setprio(1);
        acc = __builtin_amdgcn_mfma_f32_16x16x32_bf16(A0, b0, acc, 0,0,0);
        acc = __builtin_amdgcn_mfma_f32_16x16x32_bf16(A1, b1, acc, 0,0,0);
        __builtin_amdgcn_s_setprio(0);
        if (col <= 576){
          int sk = (ct >= 4);
#pragma unroll
          for (int r=0;r<4;r++){
            int row = rbase + r;
            sS[row*SSTR + col + (sk ? row : 0)] = acc[r];
          }
        }
      }
    }
  }

  int dg = wv & 3, khalf = wv >> 2;
  int dcol = dg*16 + lane15;
  const unsigned short* vtb = vt + ((size_t)(b*16+h)*64 + dcol)*4096;
  int kc0 = khalf*10, kcn = khalf ? 9 : 10;
  s16x8 vB[10];
#pragma unroll
  for (int j = 0; j < 10; ++j){
    if (j < kcn){
      int kk = (kc0 + j)*32 + kh;
      int key = (kk < 64) ? kk : (t - 320 + kk);
      key = key < 0 ? 0 : (key > 4088 ? 4088 : key);
      vB[j] = *(const s16x8*)(vtb + key);
    }
  }

  bar_lgkm();

  {
    int r0 = wv*2;
    float low_add[2], up_add[2];
#pragma unroll
    for (int rr=0;rr<2;rr++){
      int s = t + r0 + rr;
      low_add[rr] = (s >= 1) ? amask[b*4096 + s - 1] : 0.f;
      up_add[rr]  = amask[b*4096 + s];
    }
    float ereg[2][10];
    float sum4[2] = {0.f,0.f};
#pragma unroll
    for (int i=0;i<10;i++){
      int c = lane + i*64;
      bool inr = (c < 577);
      bool isup = (c >= 320), islow = (c >= 64) & !isup;
      int jup = c - 320, jlow = c - 64;
#pragma unroll
      for (int rr=0;rr<2;rr++){
        int r = r0 + rr;
        float e = 0.f;
        if (inr){
          float v = sS[r*SSTR + c + ((c>=64) ? r : 0)];
          int ii = (t + r) & 255;
          if (isup){
            bool valid = !((chk==15) & (jup >= 256 - ii));
            v = valid ? v + up_add[rr] : -1e30f;
          } else if (islow){
            bool valid = !((chk==0) & (jlow < 256 - ii));
            v = valid ? ((jlow==255) ? 0.f : v + low_add[rr]) : -1e30f;
          }
          e = __expf(v);
          ((unsigned short*)&sS[r*SSTR])[c + ((c>=64) ? r : 0)] = f2bf(e);
        }
        ereg[rr][i] = e;
        sum4[rr] += e;
      }
    }
#pragma unroll
    for (int o=32;o;o>>=1){
#pragma unroll
      for (int rr=0;rr<2;rr++) sum4[rr] += __shfl_xor(sum4[rr], o);
    }
#pragma unroll
    for (int rr=0;rr<2;rr++){
      int r = r0 + rr, s = t + r;
      float rs = 1.f / sum4[rr];
      float mz = maskb[b*4096 + s] ? 0.f : 1.f;
      float pz = (s < 64) ? 0.f : mz;
      float* prow = probs + ((size_t)(b*4096+s)*16 + h)*577;
#pragma unroll
      for (int i=0;i<10;i++){
        int c = lane + i*64;
        if (c < 577) ntst(prow + c, ereg[rr][i] * rs * pz);
      }
      if (lane < 31){
        int zc = (lane < r) ? 64 + lane : 577 + lane;
        ((unsigned short*)&sS[r*SSTR])[zc] = 0;
      }
      if (lane == 0) srs[r] = rs * mz;
    }
  }
  bar_lgkm();

  const unsigned short* prow16 = (const unsigned short*)(sS + (size_t)lane15*SSTR);
  f32x4 oacc = (f32x4){0.f,0.f,0.f,0.f};
  __builtin_amdgcn_s_setprio(1);
#pragma unroll
  for (int j = 0; j < 10; ++j){
    if (j < kcn){
      s16x8 ap = *(const s16x8*)(prow16 + (kc0 + j)*32 + kh);
      oacc = __builtin_amdgcn_mfma_f32_16x16x32_bf16(ap, vB[j], oacc, 0,0,0);
    }
  }
  __builtin_amdgcn_s_setprio(0);
  if (khalf == 1){
#pragma unroll
    for (int r=0;r<4;r++){
      int flat = dg*256 + (rbase + r)*16 + lane15;
      sS[(flat>>8)*SSTR + 336 + (flat & 255)] = oacc[r];
    }
  }
  bar_lgkm();
  if (khalf == 0){
#pragma unroll
    for (int r=0;r<4;r++){
      int flat = dg*256 + (rbase + r)*16 + lane15;
      float part = sS[(flat>>8)*SSTR + 336 + (flat & 255)];
      ntst(attn + (size_t)(b*4096 + t + rbase + r)*1024 + h*64 + dcol,
           (oacc[r] + part) * srs[rbase + r]);
    }
  }
}

// ---------------- global attention: gs = qg·kg^T via MFMA ----------------
__global__ __launch_bounds__(256) void gs_a2(
    const unsigned short* __restrict__ qg,
    const unsigned short* __restrict__ proj,
    const unsigned char* __restrict__ maskb,
    float* __restrict__ gp)
{
  __shared__ unsigned short sQ[64*68];
  int bi = blockIdx.x;
  int sc = bi & 15, h = (bi>>4) & 15, b = bi >> 8;
  int tid = threadIdx.x, lane = tid & 63, wv = tid >> 6;
  int lane15 = lane & 15, kh = (lane >> 4) << 3;
#pragma unroll
  for (int it=0; it<2; ++it){
    int flat = it*256 + tid;
    int g = flat >> 3, ch = (flat & 7) << 3;
    *(s16x8*)&sQ[g*68 + ch] = *(const s16x8*)(qg + (size_t)(b*64+g)*1024 + h*64 + ch);
  }
  __syncthreads();
  s16x8 a[4][2];
#pragma unroll
  for (int gt=0; gt<4; ++gt)
#pragma unroll
    for (int ks=0; ks<2; ++ks)
      a[gt][ks] = *(const s16x8*)&sQ[(gt*16+lane15)*68 + ks*32 + kh];
  int s0 = sc*256 + wv*64;
  float* gpb_ = gp + (size_t)(b*16+h)*64*4096;
#pragma unroll
  for (int st=0; st<4; ++st){
    int s = s0 + st*16 + lane15;
    const unsigned short* kp = proj + (size_t)(b*4096+s)*5120 + 3072 + h*64 + kh;
    s16x8 b0 = *(const s16x8*)kp;
    s16x8 b1 = *(const s16x8*)(kp + 32);
    bool msk = maskb[b*4096 + s] != 0;
    f32x4 acc[4];
#pragma unroll
    for (int gt=0; gt<4; ++gt){
      acc[gt] = (f32x4){0.f,0.f,0.f,0.f};
      acc[gt] = __builtin_amdgcn_mfma_f32_16x16x32_bf16(a[gt][0], b0, acc[gt], 0,0,0);
      acc[gt] = __builtin_amdgcn_mfma_f32_16x16x32_bf16(a[gt][1], b1, acc[gt], 0,0,0);
    }
#pragma unroll
    for (int gt=0; gt<4; ++gt){
#pragma unroll
      for (int r=0;r<4;r++){
        int g = gt*16 + (lane>>4)*4 + r;
        ntst(gpb_ + (size_t)g*4096 + s, msk ? -10000.f : acc[gt][r]);
      }
    }
  }
}

__global__ __launch_bounds__(256) void gs_norm(float* __restrict__ gp,
                                               unsigned short* __restrict__ gpb){
  __shared__ float red[8];
  int bi = blockIdx.x;
  float* row = gp + (size_t)bi*4096;
  int tid = threadIdx.x, lane = tid & 63, wv = tid >> 6;
  float v[16];
  float m = -1e30f;
#pragma unroll
  for (int i=0;i<16;i++){
    v[i] = row[tid + i*256];
    m = fmaxf(m, v[i]);
  }
#pragma unroll
  for (int o=32;o;o>>=1) m = fmaxf(m, __shfl_xor(m, o));
  if (!lane) red[wv] = m;
  __syncthreads();
  m = fmaxf(fmaxf(red[0],red[1]), fmaxf(red[2],red[3]));
  float s = 0.f;
#pragma unroll
  for (int i=0;i<16;i++){
    float e = __expf(v[i] - m);
    v[i] = e;
    s += e;
  }
#pragma unroll
  for (int o=32;o;o>>=1) s += __shfl_xor(s, o);
  if (!lane) red[4+wv] = s;
  __syncthreads();
  s = red[4]+red[5]+red[6]+red[7];
  float rs = 1.f / s;
#pragma unroll
  for (int i=0;i<16;i++){
    float p = v[i] * rs;
    ntst(row + tid + i*256, p);
    gpb[(size_t)bi*4096 + tid + i*256] = f2bf(p);
  }
}

__global__ __launch_bounds__(256) void go_mfma(
    const unsigned short* __restrict__ gpb,
    const unsigned short* __restrict__ vgt,
    float* __restrict__ gop)
{
  int bi = blockIdx.x;
  int kc = bi & 7, bh = bi >> 3;
  int tid = threadIdx.x, lane = tid & 63, wv = tid >> 6;
  int lane15 = lane & 15, kh = (lane >> 4) << 3;
  const unsigned short* arow = gpb + ((size_t)bh*64 + wv*16 + lane15)*4096 + kh;
  const unsigned short* bbase = vgt + (size_t)bh*64*4096 + kh;
  f32x4 acc[4];
#pragma unroll
  for (int j=0;j<4;j++) acc[j] = (f32x4){0.f,0.f,0.f,0.f};
  for (int ks = 0; ks < 16; ++ks){
    int k = kc*512 + ks*32;
    s16x8 a = *(const s16x8*)(arow + k);
#pragma unroll
    for (int j=0;j<4;j++){
      s16x8 bv = *(const s16x8*)(bbase + (size_t)(j*16 + lane15)*4096 + k);
      acc[j] = __builtin_amdgcn_mfma_f32_16x16x32_bf16(a, bv, acc[j], 0,0,0);
    }
  }
  int rq = (lane >> 4) << 2;
  float* o = gop + ((size_t)bh*8 + kc)*4096;
#pragma unroll
  for (int j=0;j<4;j++)
#pragma unroll
    for (int r=0;r<4;r++)
      o[(wv*16 + rq + r)*64 + j*16 + lane15] = acc[j][r];
}

__global__ __launch_bounds__(256) void reduce_go2(
    const float* __restrict__ gop, float* __restrict__ attn){
  int flat = blockIdx.x*256 + threadIdx.x;
  int gd = flat & 4095, bh = flat >> 12;
  int b = bh >> 4, h = bh & 15;
  int g = gd >> 6, d = gd & 63;
  const float* p = gop + (size_t)bh*8*4096 + gd;
  float sum = 0.f;
#pragma unroll
  for (int c=0; c<8; ++c) sum += p[c*4096];
  attn[(size_t)(b*4096 + g)*1024 + h*64 + d] = sum;
}

// ---------------- launcher ----------------
extern "C" void kernel_launch(void* const* d_in, const int* in_sizes, int n_in,
                              void* d_out, int out_size, void* d_ws, size_t ws_size,
                              hipStream_t stream)
{
  const float* X     = (const float*)d_in[0];
  const float* amask = (const float*)d_in[1];
  const float* Wq  = (const float*)d_in[2];  const float* bq  = (const float*)d_in[3];
  const float* Wk  = (const float*)d_in[4];  const float* bk  = (const float*)d_in[5];
  const float* Wv  = (const float*)d_in[6];  const float* bv  = (const float*)d_in[7];
  const float* Wqg = (const float*)d_in[8];  const float* bqg = (const float*)d_in[9];
  const float* Wkg = (const float*)d_in[10]; const float* bkg = (const float*)d_in[11];
  const float* Wvg = (const float*)d_in[12]; const float* bvg = (const float*)d_in[13];
  const unsigned char* imask = (const unsigned char*)d_in[14];
  (void)in_sizes; (void)n_in; (void)out_size;

  const size_t XBF  = 0;               // 16,777,216 (Xbf; later gp_bf)
  const size_t XG   = 16777216;        // 262,144
  const size_t WT   = 17039360;        // 10,485,760 (Wt cat; later gop 4MB + qgp 2MB)
  const size_t WTQG = 27525120;        // 2,097,152
  const size_t BC   = 29622272;        // 20,480
  const size_t BQG  = 29642752;        // 4,096
  const size_t PROJ = 29646848;        // 83,886,080
  const size_t QGO  = 113532928;       // 262,144
  const size_t VT   = 113795072;       // 16,777,216
  const size_t NEED = 130572288;
  if (ws_size < NEED) return;

  char* ws = (char*)d_ws;
  unsigned short* Xbf   = (unsigned short*)(ws + XBF);
  unsigned short* Xg    = (unsigned short*)(ws + XG);
  unsigned short* Wtcat = (unsigned short*)(ws + WT);
  unsigned short* Wtqg  = (unsigned short*)(ws + WTQG);
  float*          bc    = (float*)(ws + BC);
  float*          bqgo  = (float*)(ws + BQG);
  unsigned short* proj  = (unsigned short*)(ws + PROJ);
  unsigned short* qgo   = (unsigned short*)(ws + QGO);
  unsigned short* vt    = (unsigned short*)(ws + VT);
  unsigned short* gpb   = (unsigned short*)(ws + XBF);   // after sliding
  float*          gop   = (float*)(ws + WT);             // retired Wt (4 MB)
  float*          qgp   = (float*)(ws + WT + 4194304);   // qg partials (2 MB)

  float* attn  = (float*)d_out;
  float* probs = (float*)d_out + 8388608;
  float* gp    = (float*)d_out + 84017152;

  hipFuncSetAttribute((const void*)gemm8,
                      hipFuncAttributeMaxDynamicSharedMemorySize, G8_LDS);

  cast_x<<<8192, 256, 0, stream>>>(X, Xbf, Xg);
  bias_cat_k<<<24, 256, 0, stream>>>(bq, bk, bv, bkg, bvg, bqg, bc, bqgo);
  WSrc srcs; srcs.p[0]=Wq; srcs.p[1]=Wk; srcs.p[2]=Wv; srcs.p[3]=Wqg; srcs.p[4]=Wkg; srcs.p[5]=Wvg;
  wt_transpose<<<1536, 256, 0, stream>>>(srcs, Wtcat, Wtqg);
  gemm8<<<dim3(20,32), 512, G8_LDS, stream>>>(Xbf, Wtcat, bc, proj, vt,
                                              1024, 1024, 5120, 1024);
  gemm_qg<<<dim3(8,4), 256, 0, stream>>>(Xg, Wtqg, qgp);
  reduce_qg<<<512, 256, 0, stream>>>(qgp, bqgo, qgo);
  sliding_attn<<<8192, 512, 0, stream>>>(proj, vt, amask, imask, probs, attn);
  vt_transpose<<<2048, 256, 0, stream>>>(proj, vt, 4096);   // vg^T (vt free now)
  gs_a2<<<512, 256, 0, stream>>>(qgo, proj, imask, gp);
  gs_norm<<<2048, 256, 0, stream>>>(gp, gpb);
  go_mfma<<<256, 256, 0, stream>>>(gpb, vt, gop);
  reduce_go2<<<512, 256, 0, stream>>>(gop, attn);
}

// Round 18
// 373.881 us; speedup vs baseline: 1.0132x; 1.0132x over previous
//
#include <hip/hip_runtime.h>
#include <hip/hip_bf16.h>
#include <cstdint>
#include <cstddef>

typedef short s16x8 __attribute__((ext_vector_type(8)));
typedef float f32x4 __attribute__((ext_vector_type(4)));

#define DEV static __device__ __forceinline__

DEV unsigned short f2bf(float x){
  union { float f; unsigned int u; } v; v.f = x;
  unsigned int u = v.u;
  return (unsigned short)((u + 0x7FFFu + ((u >> 16) & 1u)) >> 16);
}
DEV float bf2f(unsigned short b){
  union { unsigned int u; float f; } v; v.u = ((unsigned int)b) << 16;
  return v.f;
}
DEV void ntst(float* p, float v){ __builtin_nontemporal_store(v, p); }

// raw workgroup barrier: wait LDS ops only (no vmcnt drain)
DEV void bar_lgkm(){
  asm volatile("s_waitcnt lgkmcnt(0)" ::: "memory");
  __builtin_amdgcn_s_barrier();
  __builtin_amdgcn_sched_barrier(0);
}

// async global->LDS 16B (wave-uniform LDS base + lane*16; global addr per-lane)
DEV void gld16(unsigned short* lds, const unsigned short* g){
  __builtin_amdgcn_global_load_lds(
      (const __attribute__((address_space(1))) void*)g,
      (__attribute__((address_space(3))) void*)lds, 16, 0, 0);
}

// ---------------- cast & gather (fused) ----------------
__global__ __launch_bounds__(256) void cast_x(const float* __restrict__ X,
                                              unsigned short* __restrict__ out,
                                              unsigned short* __restrict__ Xg){
  int i = (blockIdx.x*256 + threadIdx.x)*4;
  float4 v = *(const float4*)(X + i);
  ushort4 r;
  r.x = f2bf(v.x); r.y = f2bf(v.y); r.z = f2bf(v.z); r.w = f2bf(v.w);
  *(ushort4*)(out + i) = r;
  int row = i >> 10;                    // global row (b*4096+s)
  int s = row & 4095, b = row >> 12;
  if (s < 64)
    *(ushort4*)(Xg + (size_t)(b*64 + s)*1024 + (i & 1023)) = r;
}

__global__ __launch_bounds__(256) void bias_cat_k(
    const float* bq, const float* bk, const float* bv,
    const float* bkg, const float* bvg, const float* bqg,
    float* __restrict__ bc, float* __restrict__ bqg_o){
  int i = blockIdx.x*256 + threadIdx.x;             // < 6144
  if (i < 5120){
    int slot = i >> 10, c = i & 1023;
    const float* s = (slot==0)?bq:(slot==1)?bk:(slot==2)?bv:(slot==3)?bkg:bvg;
    bc[i] = s[c];
  } else {
    bqg_o[i-5120] = bqg[i-5120];
  }
}

// ---------------- weight transpose: W[k][n] fp32 -> Wt[n][k] bf16 ----------------
struct WSrc { const float* p[6]; };

__global__ __launch_bounds__(256) void wt_transpose(WSrc srcs,
    unsigned short* __restrict__ Wtcat, unsigned short* __restrict__ Wtqg){
  __shared__ float t[64*66];
  int bi = blockIdx.x;
  int widx = bi >> 8;                 // 0..5 input order q,k,v,qg,kg,vg
  int tile = bi & 255;
  int tn = tile & 15, tk = tile >> 4;
  int k0 = tk*64, n0 = tn*64;
  const float* W = srcs.p[widx];
  int tid = threadIdx.x;
  for (int it=0; it<8; ++it){
    int flat = it*256 + tid;          // 2048 float2
    int r = flat >> 5, ch = flat & 31;
    *(float2*)&t[r*66 + ch*2] = *(const float2*)(W + (size_t)(k0+r)*1024 + n0 + ch*2);
  }
  __syncthreads();
  unsigned short* dst = (widx==3) ? Wtqg
                      : Wtcat + (size_t)((widx<3)?widx:widx-1)*1048576;
  for (int it=0; it<16; ++it){
    int flat = it*256 + tid;          // 4096 elems
    int i = flat >> 6, j = flat & 63;
    dst[(size_t)(n0+i)*1024 + k0 + j] = f2bf(t[j*66 + i]);
  }
}

// ---------------- 256x256 counted-vmcnt pipelined GEMM (T2+T3+T4) ----------------
// 4 half-tile LDS slots (32KB each: A 128x64 + B 128x64), 2-K-tile lookahead.
// Per iter: ds_read+MFMA -> lgkm barrier -> stage 2 half-tiles into freed slots
// -> vmcnt(8) (counted, never 0 until tail) -> barrier.
#define G8_LDS 131072
__global__ __launch_bounds__(512) void gemm8(
    const unsigned short* __restrict__ A, const unsigned short* __restrict__ Bt,
    const float* __restrict__ bias, unsigned short* __restrict__ C,
    int Astr, int Bstr, int Cstr, int scale_cols)
{
  extern __shared__ unsigned short lds[];   // slot s at s*16384; B at +8192
  int tid = threadIdx.x, lane = tid & 63, wv = tid >> 6;
  int wr = wv >> 2, wc = wv & 3;            // 2M x 4N waves; per-wave 128x64
  int lane15 = lane & 15, kh = (lane >> 4) << 3;
  int m0 = blockIdx.y*256, n0 = blockIdx.x*256;

  f32x4 acc[8][4];
#pragma unroll
  for (int i=0;i<8;i++)
#pragma unroll
    for (int j=0;j<4;j++) acc[i][j] = (f32x4){0.f,0.f,0.f,0.f};

  // prologue: stage half-tiles 0..3 (K-tiles 0,1)
#pragma unroll
  for (int ht=0; ht<4; ++ht){
    int ktn = ht>>1, half = ht&1;
    unsigned short* sA = lds + (ht&3)*16384;
    unsigned short* sB = sA + 8192;
#pragma unroll
    for (int cc=0; cc<2; ++cc){
      int c = cc*512 + tid, r = c>>3, ch = c&7;
      int co = ktn*64 + ((ch ^ (r&7))<<3);
      gld16(sA + c*8, A  + (size_t)(m0 + half*128 + r)*Astr + co);
      gld16(sB + c*8, Bt + (size_t)(n0 + half*128 + r)*Bstr + co);
    }
  }
  asm volatile("s_waitcnt vmcnt(8)" ::: "memory");   // ht0,1 landed
  __builtin_amdgcn_s_barrier();
  __builtin_amdgcn_sched_barrier(0);

  for (int kt = 0; kt < 16; ++kt){
    unsigned short* aslot = lds + ((2*kt + wr)&3)*16384;
    unsigned short* bslot = lds + ((2*kt + (wc>>1))&3)*16384 + 8192;
    // B fragments (wave-fixed 64 cols)
    s16x8 bfr[4][2];
#pragma unroll
    for (int n=0;n<4;n++){
      int r = (wc&1)*64 + n*16 + lane15;
#pragma unroll
      for (int ks=0;ks<2;ks++)
        bfr[n][ks] = *(const s16x8*)&bslot[(r<<6) + ((ks*32 + kh) ^ ((r&7)<<3))];
    }
    __builtin_amdgcn_s_setprio(1);
#pragma unroll
    for (int m=0;m<8;m++){
      int r = m*16 + lane15;
      s16x8 a0 = *(const s16x8*)&aslot[(r<<6) + (kh ^ ((r&7)<<3))];
      s16x8 a1 = *(const s16x8*)&aslot[(r<<6) + ((32 + kh) ^ ((r&7)<<3))];
#pragma unroll
      for (int n=0;n<4;n++){
        acc[m][n] = __builtin_amdgcn_mfma_f32_16x16x32_bf16(a0, bfr[n][0], acc[m][n], 0,0,0);
        acc[m][n] = __builtin_amdgcn_mfma_f32_16x16x32_bf16(a1, bfr[n][1], acc[m][n], 0,0,0);
      }
    }
    __builtin_amdgcn_s_setprio(0);
    bar_lgkm();                    // all waves done reading slots (2kt),(2kt+1)
    if (kt < 14){
      // stage ht 2kt+4, 2kt+5 into the two slots just freed
#pragma unroll
      for (int hh=0; hh<2; ++hh){
        int ht = 2*kt + 4 + hh;
        int ktn = ht>>1, half = ht&1;
        unsigned short* sA = lds + (ht&3)*16384;
        unsigned short* sB = sA + 8192;
#pragma unroll
        for (int cc=0; cc<2; ++cc){
          int c = cc*512 + tid, r = c>>3, ch = c&7;
          int co = ktn*64 + ((ch ^ (r&7))<<3);
          gld16(sA + c*8, A  + (size_t)(m0 + half*128 + r)*Astr + co);
          gld16(sB + c*8, Bt + (size_t)(n0 + half*128 + r)*Bstr + co);
        }
      }
      asm volatile("s_waitcnt vmcnt(8)" ::: "memory");  // ht 2kt+2,2kt+3 landed
    } else {
      asm volatile("s_waitcnt vmcnt(0)" ::: "memory");  // tail drain
    }
    __builtin_amdgcn_s_barrier();
    __builtin_amdgcn_sched_barrier(0);
  }

  // epilogue: C[m0+wr*128+.., n0+wc*64+..]
#pragma unroll
  for (int m=0;m<8;m++){
    int mb = m0 + wr*128 + m*16 + ((lane>>4)<<2);
#pragma unroll
    for (int n=0;n<4;n++){
      int col = n0 + wc*64 + n*16 + lane15;
      float bb = bias[col];
      float sc = (col < scale_cols) ? 0.125f : 1.0f;
#pragma unroll
      for (int r=0;r<4;r++)
        C[(size_t)(mb+r)*Cstr + col] = f2bf((acc[m][n][r] + bb)*sc);
    }
  }
}

// ---------------- bf16 MFMA GEMM (m97 + T2 swizzle) — small qg GEMM ----------------
__global__ __launch_bounds__(256) void gemm_bt(
    const unsigned short* __restrict__ A, const unsigned short* __restrict__ Bt,
    const float* __restrict__ bias, unsigned short* __restrict__ C,
    int Astr, int Bstr, int Cstr, int scale_cols)
{
  __shared__ unsigned short lA[128*64];
  __shared__ unsigned short lB[128*64];
  int tid = threadIdx.x, lane = tid & 63, wv = tid >> 6;
  int wm = wv >> 1, wn = wv & 1;
  int lane15 = lane & 15, kh = (lane >> 4) << 3;
  int m0 = blockIdx.y*128, n0 = blockIdx.x*128;
  f32x4 acc[4][4];
  for (int i=0;i<4;i++) for (int j=0;j<4;j++) acc[i][j] = (f32x4){0.f,0.f,0.f,0.f};
  for (int k0 = 0; k0 < 1024; k0 += 64){
#pragma unroll
    for (int it = 0; it < 4; ++it){
      int chunk = it*256 + tid;       // 1024 chunks of 16B per 128x64 tile
      int r = chunk >> 3, ch = chunk & 7;
      int co = ((ch ^ (r & 7)) << 3);
      gld16(&lA[chunk*8], A  + (size_t)(m0+r)*Astr + k0 + co);
      gld16(&lB[chunk*8], Bt + (size_t)(n0+r)*Bstr + k0 + co);
    }
    __syncthreads();
#pragma unroll
    for (int ks = 0; ks < 2; ++ks){
      s16x8 af[4], bfr[4];
#pragma unroll
      for (int i=0;i<4;i++){
        int row = wm*64 + i*16 + lane15;
        af[i] = *(const s16x8*)&lA[(row<<6) + ((ks*32 + kh) ^ ((row&7)<<3))];
      }
#pragma unroll
      for (int j=0;j<4;j++){
        int row = wn*64 + j*16 + lane15;
        bfr[j] = *(const s16x8*)&lB[(row<<6) + ((ks*32 + kh) ^ ((row&7)<<3))];
      }
#pragma unroll
      for (int i=0;i<4;i++)
#pragma unroll
        for (int j=0;j<4;j++)
          acc[i][j] = __builtin_amdgcn_mfma_f32_16x16x32_bf16(af[i], bfr[j], acc[i][j], 0,0,0);
    }
    __syncthreads();
  }
  for (int i=0;i<4;i++){
    int mb = m0 + wm*64 + i*16 + ((lane>>4)<<2);
    for (int j=0;j<4;j++){
      int n = n0 + wn*64 + j*16 + lane15;
      float bb = bias[n];
      float sc = (n < scale_cols) ? 0.125f : 1.0f;
#pragma unroll
      for (int r=0;r<4;r++)
        C[(size_t)(mb+r)*Cstr + n] = f2bf((acc[i][j][r] + bb)*sc);
    }
  }
}

// ---------------- proj col-slice -> t[b][h][d][s] (s-contiguous) ----------------
__global__ __launch_bounds__(256) void vt_transpose(
    const unsigned short* __restrict__ proj, unsigned short* __restrict__ dst,
    int coloff){
  __shared__ unsigned short t[64*72];
  int bi = blockIdx.x;
  int sc = bi & 63, h = (bi>>6) & 15, b = bi >> 10;
  int s0 = sc*64;
  int tid = threadIdx.x;
  for (int it=0; it<2; ++it){
    int flat = it*256 + tid;          // 512 16B-chunks
    int r = flat >> 3, ch = flat & 7;
    *(int4*)&t[r*72 + ch*8] =
      *(const int4*)(proj + (size_t)(b*4096+s0+r)*5120 + coloff + h*64 + ch*8);
  }
  __syncthreads();
  for (int it=0; it<2; ++it){
    int flat = it*256 + tid;
    int d = flat & 63, ch = flat >> 6; // 0..7
    unsigned short tmp[8];
#pragma unroll
    for (int j=0;j<8;j++) tmp[j] = t[(ch*8+j)*72 + d];
    *(int4*)(dst + ((size_t)(b*16+h)*64 + d)*4096 + s0 + ch*8) = *(int4*)tmp;
  }
}

// ---------------- fused sliding-window + global-prefix attention ----------------
#define SSTR 612
__global__ __launch_bounds__(512) void sliding_attn(
    const unsigned short* __restrict__ proj,   // [8192][5120]: q|k|v|kg|vg
    const unsigned short* __restrict__ vt,     // [2][16][64][4096]
    const float* __restrict__ amask,           // [2][4096]
    const unsigned char* __restrict__ maskb,   // is_index_masked (all 0)
    float* __restrict__ probs,                 // [2][4096][16][577]
    float* __restrict__ attn)                  // [2][4096][1024]
{
  __shared__ float sS[16*SSTR];                // 39168 B (scores f32 -> e bf16)
  __shared__ float srs[16];                    // per-row rs*mz for PV epilogue
  int bi = (blockIdx.x & 7)*1024 + (blockIdx.x >> 3);   // XCD-contiguous work id
  int ti = bi & 255, h = (bi>>8) & 15, b = bi >> 12;
  int t = ti*16;
  int chk = t >> 8;
  int qu = (chk < 15) ? chk*256 : 3584;
  int ql = (chk >= 1) ? chk*256 : 256;
  int tid = threadIdx.x, lane = tid & 63, wv = tid >> 6;  // wv 0..7
  int lane15 = lane & 15, kh = (lane >> 4) << 3;
  int rbase = (lane>>4)<<2;

  // A fragments, loaded only by waves whose tile range needs them (wave-uniform)
  s16x8 aq0 = {}, aq1 = {}, ak0a = {}, ak0b = {}, ak1a = {}, ak1b = {};
  {
    int qrow = t + lane15;
    if (wv == 0){
      const unsigned short* qp = proj + (size_t)(b*4096+qrow)*5120 + h*64 + kh;
      aq0 = *(const s16x8*)qp;  aq1 = *(const s16x8*)(qp + 32);
    }
    if (wv >= 4){              // up tiles 20..36
      const unsigned short* kp0 = proj + (size_t)(b*4096+qrow)*5120 + 1024 + h*64 + kh;
      ak0a = *(const s16x8*)kp0; ak0b = *(const s16x8*)(kp0 + 32);
    }
    if (wv <= 3){              // low tiles 4..19 (+ global handled by wv0)
      int krow = t - 1 + lane15; if (krow < 0) krow = 0;
      const unsigned short* kp1 = proj + (size_t)(b*4096+krow)*5120 + 1024 + h*64 + kh;
      ak1a = *(const s16x8*)kp1; ak1b = *(const s16x8*)(kp1 + 32);
    }
  }

  // QK: wave wv owns tiles [5wv, 5wv+5)
  {
    int ct0 = wv*5;
#pragma unroll
    for (int j5 = 0; j5 < 5; ++j5){
      int ct = ct0 + j5;
      if (ct < 37){
        int col = ct*16 + lane15;
        int brow, roff;
        if (ct < 4){        brow = col;               roff = 1024; }
        else if (ct < 20){  brow = ql + 1 + col - 64; roff = 0;
                            if (brow > 4095) brow = 4095; }
        else {              brow = qu + col - 320;    roff = 0; }
        const unsigned short* bp = proj + (size_t)(b*4096+brow)*5120 + roff + h*64 + kh;
        s16x8 b0 = *(const s16x8*)bp;
        s16x8 b1 = *(const s16x8*)(bp + 32);
        s16x8 A0 = (ct<4) ? aq0 : (ct<20) ? ak1a : ak0a;
        s16x8 A1 = (ct<4) ? aq1 : (ct<20) ? ak1b : ak0b;
        f32x4 acc = (f32x4){0.f,0.f,0.f,0.f};
        __builtin_amdgcn_s_setprio(1);
        acc = __builtin_amdgcn_mfma_f32_16x16x32_bf16(A0, b0, acc, 0,0,0);
        acc = __builtin_amdgcn_mfma_f32_16x16x32_bf16(A1, b1, acc, 0,0,0);
        __builtin_amdgcn_s_setprio(0);
        if (col <= 576){
          int sk = (ct >= 4);
#pragma unroll
          for (int r=0;r<4;r++){
            int row = rbase + r;
            sS[row*SSTR + col + (sk ? row : 0)] = acc[r];
          }
        }
      }
    }
  }

  // T14 issue-early: PV V-fragments (independent of softmax)
  int dg = wv & 3, khalf = wv >> 2;
  int dcol = dg*16 + lane15;
  const unsigned short* vtb = vt + ((size_t)(b*16+h)*64 + dcol)*4096;
  int kc0 = khalf*10, kcn = khalf ? 9 : 10;
  s16x8 vB[10];
#pragma unroll
  for (int j = 0; j < 10; ++j){
    if (j < kcn){
      int kk = (kc0 + j)*32 + kh;
      int key = (kk < 64) ? kk : (t - 320 + kk);
      key = key < 0 ? 0 : (key > 4088 ? 4088 : key);
      vB[j] = *(const s16x8*)(vtb + key);
    }
  }

  bar_lgkm();

  // softmax: wave wv owns rows 2wv, 2wv+1; single pass; nt probs stores
  {
    int r0 = wv*2;
    float low_add[2], up_add[2];
#pragma unroll
    for (int rr=0;rr<2;rr++){
      int s = t + r0 + rr;
      low_add[rr] = (s >= 1) ? amask[b*4096 + s - 1] : 0.f;
      up_add[rr]  = amask[b*4096 + s];
    }
    float ereg[2][10];
    float sum4[2] = {0.f,0.f};
#pragma unroll
    for (int i=0;i<10;i++){
      int c = lane + i*64;
      bool inr = (c < 577);
      bool isup = (c >= 320), islow = (c >= 64) & !isup;
      int jup = c - 320, jlow = c - 64;
#pragma unroll
      for (int rr=0;rr<2;rr++){
        int r = r0 + rr;
        float e = 0.f;
        if (inr){
          float v = sS[r*SSTR + c + ((c>=64) ? r : 0)];
          int ii = (t + r) & 255;
          if (isup){
            bool valid = !((chk==15) & (jup >= 256 - ii));
            v = valid ? v + up_add[rr] : -1e30f;
          } else if (islow){
            bool valid = !((chk==0) & (jlow < 256 - ii));
            v = valid ? ((jlow==255) ? 0.f : v + low_add[rr]) : -1e30f;
          }
          e = __expf(v);
          ((unsigned short*)&sS[r*SSTR])[c + ((c>=64) ? r : 0)] = f2bf(e);
        }
        ereg[rr][i] = e;
        sum4[rr] += e;
      }
    }
#pragma unroll
    for (int o=32;o;o>>=1){
#pragma unroll
      for (int rr=0;rr<2;rr++) sum4[rr] += __shfl_xor(sum4[rr], o);
    }
#pragma unroll
    for (int rr=0;rr<2;rr++){
      int r = r0 + rr, s = t + r;
      float rs = 1.f / sum4[rr];
      float mz = maskb[b*4096 + s] ? 0.f : 1.f;
      float pz = (s < 64) ? 0.f : mz;
      float* prow = probs + ((size_t)(b*4096+s)*16 + h)*577;
#pragma unroll
      for (int i=0;i<10;i++){
        int c = lane + i*64;
        if (c < 577) ntst(prow + c, ereg[rr][i] * rs * pz);
      }
      if (lane < 31){
        int zc = (lane < r) ? 64 + lane : 577 + lane;
        ((unsigned short*)&sS[r*SSTR])[zc] = 0;
      }
      if (lane == 0) srs[r] = rs * mz;
    }
  }
  bar_lgkm();

  // PV: V in registers (vB), P from LDS
  const unsigned short* prow16 = (const unsigned short*)(sS + (size_t)lane15*SSTR);
  f32x4 oacc = (f32x4){0.f,0.f,0.f,0.f};
  __builtin_amdgcn_s_setprio(1);
#pragma unroll
  for (int j = 0; j < 10; ++j){
    if (j < kcn){
      s16x8 ap = *(const s16x8*)(prow16 + (kc0 + j)*32 + kh);
      oacc = __builtin_amdgcn_mfma_f32_16x16x32_bf16(ap, vB[j], oacc, 0,0,0);
    }
  }
  __builtin_amdgcn_s_setprio(0);
  if (khalf == 1){
#pragma unroll
    for (int r=0;r<4;r++){
      int flat = dg*256 + (rbase + r)*16 + lane15;
      sS[(flat>>8)*SSTR + 336 + (flat & 255)] = oacc[r];
    }
  }
  bar_lgkm();
  if (khalf == 0){
#pragma unroll
    for (int r=0;r<4;r++){
      int flat = dg*256 + (rbase + r)*16 + lane15;
      float part = sS[(flat>>8)*SSTR + 336 + (flat & 255)];
      ntst(attn + (size_t)(b*4096 + t + rbase + r)*1024 + h*64 + dcol,
           (oacc[r] + part) * srs[rbase + r]);
    }
  }
}

// ---------------- global attention: gs = qg·kg^T via MFMA ----------------
__global__ __launch_bounds__(256) void gs_a2(
    const unsigned short* __restrict__ qg,     // [128][1024]
    const unsigned short* __restrict__ proj,   // kg at col 3072
    const unsigned char* __restrict__ maskb,
    float* __restrict__ gp)                    // [2][16][64][4096] raw
{
  __shared__ unsigned short sQ[64*68];
  int bi = blockIdx.x;
  int sc = bi & 15, h = (bi>>4) & 15, b = bi >> 8;
  int tid = threadIdx.x, lane = tid & 63, wv = tid >> 6;
  int lane15 = lane & 15, kh = (lane >> 4) << 3;
#pragma unroll
  for (int it=0; it<2; ++it){
    int flat = it*256 + tid;          // 512 chunks of 8 shorts
    int g = flat >> 3, ch = (flat & 7) << 3;
    *(s16x8*)&sQ[g*68 + ch] = *(const s16x8*)(qg + (size_t)(b*64+g)*1024 + h*64 + ch);
  }
  __syncthreads();
  s16x8 a[4][2];
#pragma unroll
  for (int gt=0; gt<4; ++gt)
#pragma unroll
    for (int ks=0; ks<2; ++ks)
      a[gt][ks] = *(const s16x8*)&sQ[(gt*16+lane15)*68 + ks*32 + kh];
  int s0 = sc*256 + wv*64;
  float* gpb_ = gp + (size_t)(b*16+h)*64*4096;
#pragma unroll
  for (int st=0; st<4; ++st){
    int s = s0 + st*16 + lane15;
    const unsigned short* kp = proj + (size_t)(b*4096+s)*5120 + 3072 + h*64 + kh;
    s16x8 b0 = *(const s16x8*)kp;
    s16x8 b1 = *(const s16x8*)(kp + 32);
    bool msk = maskb[b*4096 + s] != 0;
    f32x4 acc[4];
#pragma unroll
    for (int gt=0; gt<4; ++gt){
      acc[gt] = (f32x4){0.f,0.f,0.f,0.f};
      acc[gt] = __builtin_amdgcn_mfma_f32_16x16x32_bf16(a[gt][0], b0, acc[gt], 0,0,0);
      acc[gt] = __builtin_amdgcn_mfma_f32_16x16x32_bf16(a[gt][1], b1, acc[gt], 0,0,0);
    }
#pragma unroll
    for (int gt=0; gt<4; ++gt){
#pragma unroll
      for (int r=0;r<4;r++){
        int g = gt*16 + (lane>>4)*4 + r;
        ntst(gpb_ + (size_t)g*4096 + s, msk ? -10000.f : acc[gt][r]);
      }
    }
  }
}

// normalize gp rows in place (softmax over s), single pass, also emit bf16 copy
__global__ __launch_bounds__(256) void gs_norm(float* __restrict__ gp,
                                               unsigned short* __restrict__ gpb){
  __shared__ float red[8];
  int bi = blockIdx.x;                          // b*1024 + h*64 + g
  float* row = gp + (size_t)bi*4096;
  int tid = threadIdx.x, lane = tid & 63, wv = tid >> 6;
  float v[16];
  float m = -1e30f;
#pragma unroll
  for (int i=0;i<16;i++){
    v[i] = row[tid + i*256];
    m = fmaxf(m, v[i]);
  }
#pragma unroll
  for (int o=32;o;o>>=1) m = fmaxf(m, __shfl_xor(m, o));
  if (!lane) red[wv] = m;
  __syncthreads();
  m = fmaxf(fmaxf(red[0],red[1]), fmaxf(red[2],red[3]));
  float s = 0.f;
#pragma unroll
  for (int i=0;i<16;i++){
    float e = __expf(v[i] - m);
    v[i] = e;
    s += e;
  }
#pragma unroll
  for (int o=32;o;o>>=1) s += __shfl_xor(s, o);
  if (!lane) red[4+wv] = s;
  __syncthreads();
  s = red[4]+red[5]+red[6]+red[7];
  float rs = 1.f / s;
#pragma unroll
  for (int i=0;i<16;i++){
    float p = v[i] * rs;
    ntst(row + tid + i*256, p);
    gpb[(size_t)bi*4096 + tid + i*256] = f2bf(p);
  }
}

// go partial GEMM: gop[bh][kc][64][64] = gp_bf[bh][g][kslice]·vgt[bh][d][kslice]^T
__global__ __launch_bounds__(256) void go_mfma(
    const unsigned short* __restrict__ gpb,    // [32][64][4096] bf16
    const unsigned short* __restrict__ vgt,    // [32][64][4096] bf16
    float* __restrict__ gop)                   // [32][8][64][64] f32
{
  int bi = blockIdx.x;
  int kc = bi & 7, bh = bi >> 3;
  int tid = threadIdx.x, lane = tid & 63, wv = tid >> 6;
  int lane15 = lane & 15, kh = (lane >> 4) << 3;
  const unsigned short* arow = gpb + ((size_t)bh*64 + wv*16 + lane15)*4096 + kh;
  const unsigned short* bbase = vgt + (size_t)bh*64*4096 + kh;
  f32x4 acc[4];
#pragma unroll
  for (int j=0;j<4;j++) acc[j] = (f32x4){0.f,0.f,0.f,0.f};
  for (int ks = 0; ks < 16; ++ks){
    int k = kc*512 + ks*32;
    s16x8 a = *(const s16x8*)(arow + k);
#pragma unroll
    for (int j=0;j<4;j++){
      s16x8 bv = *(const s16x8*)(bbase + (size_t)(j*16 + lane15)*4096 + k);
      acc[j] = __builtin_amdgcn_mfma_f32_16x16x32_bf16(a, bv, acc[j], 0,0,0);
    }
  }
  int rq = (lane >> 4) << 2;
  float* o = gop + ((size_t)bh*8 + kc)*4096;
#pragma unroll
  for (int j=0;j<4;j++)
#pragma unroll
    for (int r=0;r<4;r++)
      o[(wv*16 + rq + r)*64 + j*16 + lane15] = acc[j][r];
}

__global__ __launch_bounds__(256) void reduce_go2(
    const float* __restrict__ gop, float* __restrict__ attn){
  int flat = blockIdx.x*256 + threadIdx.x;    // < 131072
  int gd = flat & 4095, bh = flat >> 12;
  int b = bh >> 4, h = bh & 15;
  int g = gd >> 6, d = gd & 63;
  const float* p = gop + (size_t)bh*8*4096 + gd;
  float sum = 0.f;
#pragma unroll
  for (int c=0; c<8; ++c) sum += p[c*4096];
  attn[(size_t)(b*4096 + g)*1024 + h*64 + d] = sum;
}

// ---------------- launcher ----------------
extern "C" void kernel_launch(void* const* d_in, const int* in_sizes, int n_in,
                              void* d_out, int out_size, void* d_ws, size_t ws_size,
                              hipStream_t stream)
{
  const float* X     = (const float*)d_in[0];
  const float* amask = (const float*)d_in[1];
  const float* Wq  = (const float*)d_in[2];  const float* bq  = (const float*)d_in[3];
  const float* Wk  = (const float*)d_in[4];  const float* bk  = (const float*)d_in[5];
  const float* Wv  = (const float*)d_in[6];  const float* bv  = (const float*)d_in[7];
  const float* Wqg = (const float*)d_in[8];  const float* bqg = (const float*)d_in[9];
  const float* Wkg = (const float*)d_in[10]; const float* bkg = (const float*)d_in[11];
  const float* Wvg = (const float*)d_in[12]; const float* bvg = (const float*)d_in[13];
  const unsigned char* imask = (const unsigned char*)d_in[14];
  (void)in_sizes; (void)n_in; (void)out_size;

  // ws layout (bytes)
  const size_t XBF  = 0;               // 16,777,216 (Xbf; later gp_bf)
  const size_t XG   = 16777216;        // 262,144
  const size_t WT   = 17039360;        // 10,485,760 (Wt cat; later gop 4 MB)
  const size_t WTQG = 27525120;        // 2,097,152
  const size_t BC   = 29622272;        // 20,480
  const size_t BQG  = 29642752;        // 4,096
  const size_t PROJ = 29646848;        // 83,886,080 ([8192][5120] bf16)
  const size_t QGO  = 113532928;       // 262,144
  const size_t VT   = 113795072;       // 16,777,216 (v^T; later vg^T — reuse)
  const size_t NEED = 130572288;
  if (ws_size < NEED) return;          // fail loudly (output stays poisoned)

  char* ws = (char*)d_ws;
  unsigned short* Xbf   = (unsigned short*)(ws + XBF);
  unsigned short* Xg    = (unsigned short*)(ws + XG);
  unsigned short* Wtcat = (unsigned short*)(ws + WT);
  unsigned short* Wtqg  = (unsigned short*)(ws + WTQG);
  float*          bc    = (float*)(ws + BC);
  float*          bqgo  = (float*)(ws + BQG);
  unsigned short* proj  = (unsigned short*)(ws + PROJ);
  unsigned short* qgo   = (unsigned short*)(ws + QGO);
  unsigned short* vt    = (unsigned short*)(ws + VT);
  unsigned short* gpb   = (unsigned short*)(ws + XBF);   // reuse Xbf after sliding
  float*          gop   = (float*)(ws + WT);             // reuse Wt region (4 MB)

  float* attn  = (float*)d_out;
  float* probs = (float*)d_out + 8388608;
  float* gp    = (float*)d_out + 84017152;

  hipFuncSetAttribute((const void*)gemm8,
                      hipFuncAttributeMaxDynamicSharedMemorySize, G8_LDS);

  cast_x<<<8192, 256, 0, stream>>>(X, Xbf, Xg);
  bias_cat_k<<<24, 256, 0, stream>>>(bq, bk, bv, bkg, bvg, bqg, bc, bqgo);
  WSrc srcs; srcs.p[0]=Wq; srcs.p[1]=Wk; srcs.p[2]=Wv; srcs.p[3]=Wqg; srcs.p[4]=Wkg; srcs.p[5]=Wvg;
  wt_transpose<<<1536, 256, 0, stream>>>(srcs, Wtcat, Wtqg);
  gemm8<<<dim3(20,32), 512, G8_LDS, stream>>>(Xbf, Wtcat, bc, proj, 1024, 1024, 5120, 1024);
  gemm_bt<<<dim3(8,1), 256, 0, stream>>>(Xg, Wtqg, bqgo, qgo, 1024, 1024, 1024, 1024);
  vt_transpose<<<2048, 256, 0, stream>>>(proj, vt, 2048);        // v^T
  sliding_attn<<<8192, 512, 0, stream>>>(proj, vt, amask, imask, probs, attn);
  vt_transpose<<<2048, 256, 0, stream>>>(proj, vt, 4096);        // vg^T (reuse buffer)
  gs_a2<<<512, 256, 0, stream>>>(qgo, proj, imask, gp);
  gs_norm<<<2048, 256, 0, stream>>>(gp, gpb);
  go_mfma<<<256, 256, 0, stream>>>(gpb, vt, gop);
  reduce_go2<<<512, 256, 0, stream>>>(gop, attn);
}